// Round 5
// baseline (355.333 us; speedup 1.0000x reference)
//
#include <hip/hip_runtime.h>
#include <cstdint>
#include <cstddef>

#define TT 4096   // T = H*W
#define CCH 256   // C

typedef __attribute__((ext_vector_type(8))) short short8;
typedef __attribute__((ext_vector_type(4))) float f32x4;

__device__ __forceinline__ float bf2f(unsigned int u){
  union { unsigned int i; float f; } v; v.i = u << 16; return v.f;
}
__device__ __forceinline__ unsigned short f2bf(float f){      // RNE
  unsigned int x = __float_as_uint(f);
  x += 0x7fffu + ((x >> 16) & 1u);
  return (unsigned short)(x >> 16);
}
__device__ __forceinline__ unsigned short f2bf_t(float f){    // truncate (p in [0,1])
  return (unsigned short)(__float_as_uint(f) >> 16);
}

// ---------------- Kernel 0: f32 -> bf16 weight convert ----------------------
__global__ __launch_bounds__(256)
void wconv(const float* __restrict__ src, unsigned short* __restrict__ dst){
  int i = blockIdx.x * 256 + threadIdx.x;
  float4 u = *(const float4*)(src + (size_t)i * 4);
  ushort4 r; r.x = f2bf(u.x); r.y = f2bf(u.y); r.z = f2bf(u.z); r.w = f2bf(u.w);
  *(ushort4*)(dst + (size_t)i * 4) = r;
}

// ---------------- Kernel 1: GroupNorm partial sums (atomic) -----------------
__global__ __launch_bounds__(256)
void gn_stats_part(const float* __restrict__ x, float* __restrict__ sums){
  int sg = blockIdx.x >> 2, part = blockIdx.x & 3;
  const float4* p = (const float4*)(x + (size_t)sg * 32768 + (size_t)part * 8192);
  int tid = threadIdx.x;
  float s = 0.f, sq = 0.f;
  #pragma unroll
  for (int it = 0; it < 8; ++it){
    float4 u = p[it * 256 + tid];
    s  += u.x + u.y + u.z + u.w;
    sq += u.x*u.x + u.y*u.y + u.z*u.z + u.w*u.w;
  }
  #pragma unroll
  for (int off = 32; off >= 1; off >>= 1){
    s  += __shfl_down(s, off);
    sq += __shfl_down(sq, off);
  }
  __shared__ float ls[4], lq[4];
  int w_ = tid >> 6, lane = tid & 63;
  if (lane == 0){ ls[w_] = s; lq[w_] = sq; }
  __syncthreads();
  if (tid == 0){
    atomicAdd(&sums[2*sg],   ls[0]+ls[1]+ls[2]+ls[3]);
    atomicAdd(&sums[2*sg+1], lq[0]+lq[1]+lq[2]+lq[3]);
  }
}

// ---------------- Kernel 2: GN apply + transpose -> xnT bf16 [b][t][256] ----
__global__ __launch_bounds__(256)
void gn_apply_t(const float* __restrict__ x, const float* __restrict__ gw,
                const float* __restrict__ gb, const float* __restrict__ sums,
                unsigned short* __restrict__ xnT){
  __shared__ unsigned short t_lds[64][72];
  int tid = threadIdx.x;
  int t0 = blockIdx.x << 6, c0 = blockIdx.y << 6, b = blockIdx.z;
  int t4 = (tid & 15) << 2, cr = tid >> 4;
  #pragma unroll
  for (int pass = 0; pass < 4; ++pass){
    int cl = (pass << 4) + cr;
    int c = c0 + cl;
    int sg = (b << 5) | (c >> 3);
    float s = sums[2*sg], q = sums[2*sg+1];
    float mean = s * (1.f/32768.f);
    float var  = q * (1.f/32768.f) - mean*mean;
    float rstd = rsqrtf(var + 1e-5f);
    float sc = gw[c] * rstd;
    float sh = gb[c] - mean * sc;
    float4 u = *(const float4*)(x + ((size_t)(b*CCH + c))*TT + t0 + t4);
    t_lds[t4+0][cl] = f2bf(u.x*sc + sh);
    t_lds[t4+1][cl] = f2bf(u.y*sc + sh);
    t_lds[t4+2][cl] = f2bf(u.z*sc + sh);
    t_lds[t4+3][cl] = f2bf(u.w*sc + sh);
  }
  __syncthreads();
  #pragma unroll
  for (int pass = 0; pass < 2; ++pass){
    int chunk = (pass << 8) + tid;
    int row = chunk >> 3, c8 = (chunk & 7) << 3;
    *(uint4*)(xnT + ((size_t)b*TT + t0 + row)*256 + c0 + c8) = *(const uint4*)&t_lds[row][c8];
  }
}

// ---------------- Kernel 3: QKV GEMM (bf16 MFMA), 128-o blocks --------------
// grid (64 t-tiles, 6 o-groups, 4 b); wave owns 2 strips of 16 o.
__global__ __launch_bounds__(256)
void qkv_mfma(const unsigned short* __restrict__ wb, const float* __restrict__ bias,
              const unsigned short* __restrict__ xnT,
              unsigned short* __restrict__ qT, unsigned short* __restrict__ kT,
              unsigned short* __restrict__ vO){
  __shared__ unsigned short x_lds[64][72];
  int tid = threadIdx.x;
  int w = tid >> 6, lane = tid & 63, quad = lane >> 4, l15 = lane & 15;
  int t0 = blockIdx.x << 6, og = blockIdx.y, b = blockIdx.z;
  int o0 = og << 7;
  const unsigned short* xb = xnT + (size_t)b * TT * 256;
  const unsigned short* wrow0 = wb + (size_t)(o0 + (w << 4) + l15) * 256;
  const unsigned short* wrow1 = wrow0 + (size_t)64 * 256;
  f32x4 acc[2][4];
  #pragma unroll
  for (int s = 0; s < 2; ++s)
    #pragma unroll
    for (int nt = 0; nt < 4; ++nt) acc[s][nt] = (f32x4){0.f,0.f,0.f,0.f};
  for (int ks = 0; ks < 4; ++ks){
    int k0 = ks << 6;
    __syncthreads();
    #pragma unroll
    for (int pass = 0; pass < 2; ++pass){
      int chunk = (pass << 8) + tid;
      int row = chunk >> 3, c8 = (chunk & 7) << 3;
      *(uint4*)&x_lds[row][c8] = *(const uint4*)(xb + (size_t)(t0 + row)*256 + k0 + c8);
    }
    __syncthreads();
    short8 wa[2][2];
    wa[0][0] = *(const short8*)(wrow0 + k0 + (quad << 3));
    wa[0][1] = *(const short8*)(wrow0 + k0 + 32 + (quad << 3));
    wa[1][0] = *(const short8*)(wrow1 + k0 + (quad << 3));
    wa[1][1] = *(const short8*)(wrow1 + k0 + 32 + (quad << 3));
    #pragma unroll
    for (int nt = 0; nt < 4; ++nt){
      short8 xb0 = *(const short8*)&x_lds[(nt << 4) + l15][quad << 3];
      short8 xb1 = *(const short8*)&x_lds[(nt << 4) + l15][32 + (quad << 3)];
      #pragma unroll
      for (int s = 0; s < 2; ++s){
        acc[s][nt] = __builtin_amdgcn_mfma_f32_16x16x32_bf16(wa[s][0], xb0, acc[s][nt], 0, 0, 0);
        acc[s][nt] = __builtin_amdgcn_mfma_f32_16x16x32_bf16(wa[s][1], xb1, acc[s][nt], 0, 0, 0);
      }
    }
  }
  int sec = og >> 1;
  #pragma unroll
  for (int s = 0; s < 2; ++s){
    int h = ((og & 1) << 1) + s;
    int bh = (b << 2) | h;
    float bs[4];
    #pragma unroll
    for (int r = 0; r < 4; ++r) bs[r] = bias[o0 + (s << 6) + (w << 4) + (quad << 2) + r];
    __syncthreads();                 // x_lds free (k-loop or prior strip done)
    if (sec < 2){                    // q/k -> [bh][t][64] via LDS transpose
      float qsc = (sec == 0) ? 0.125f * 1.44269504f : 1.0f;
      #pragma unroll
      for (int nt = 0; nt < 4; ++nt){
        ushort4 pk;
        pk.x = f2bf((acc[s][nt][0] + bs[0]) * qsc);
        pk.y = f2bf((acc[s][nt][1] + bs[1]) * qsc);
        pk.z = f2bf((acc[s][nt][2] + bs[2]) * qsc);
        pk.w = f2bf((acc[s][nt][3] + bs[3]) * qsc);
        *(ushort4*)&x_lds[(nt << 4) + l15][(w << 4) + (quad << 2)] = pk;
      }
      __syncthreads();
      unsigned short* dst = (sec == 0) ? qT : kT;
      #pragma unroll
      for (int pass = 0; pass < 2; ++pass){
        int chunk = (pass << 8) + tid;
        int row = chunk >> 3, c8 = (chunk & 7) << 3;
        *(uint4*)(dst + ((size_t)bh*TT + t0 + row)*64 + c8) = *(const uint4*)&x_lds[row][c8];
      }
    } else {                         // v -> [bh][64][T] natural
      #pragma unroll
      for (int nt = 0; nt < 4; ++nt)
        #pragma unroll
        for (int r = 0; r < 4; ++r)
          x_lds[(w << 4) + (quad << 2) + r][(nt << 4) + l15] = f2bf(acc[s][nt][r] + bs[r]);
      __syncthreads();
      #pragma unroll
      for (int pass = 0; pass < 2; ++pass){
        int chunk = (pass << 8) + tid;
        int row = chunk >> 3, c8 = (chunk & 7) << 3;
        *(uint4*)(vO + ((size_t)bh*64 + row)*TT + t0 + c8) = *(const uint4*)&x_lds[row][c8];
      }
    }
  }
}

// ---------------- Kernel 4: flash attention, barrier-free K-loop ------------
// block = (bh, 128 q); 4 waves x 32 q. K/V MFMA fragments loaded DIRECT from
// global (L1/L2-served; wave-identical across the block). P round-trips via
// wave-private LDS rows -> no __syncthreads in the 64-iter loop. K fragments
// software-pipelined one iteration ahead.
__global__ __launch_bounds__(256, 2)
void attn3(const unsigned short* __restrict__ qT, const unsigned short* __restrict__ kT,
           const unsigned short* __restrict__ vO, unsigned short* __restrict__ aT){
  __shared__ __align__(16) unsigned short p_lds[128][72];   // [t][s]; reused as O[t][c]
  int tid = threadIdx.x;
  int w = tid >> 6, lane = tid & 63, quad = lane >> 4, l15 = lane & 15;
  int qt5 = blockIdx.x & 31, bh = blockIdx.x >> 5;
  int t0 = qt5 << 7;
  const unsigned short* qg = qT + (size_t)bh * TT * 64;
  const unsigned short* kg = kT + (size_t)bh * TT * 64;
  const unsigned short* vg = vO + (size_t)bh * 64 * TT;
  int tw = t0 + (w << 5);

  short8 qf[2][2];
  #pragma unroll
  for (int qt = 0; qt < 2; ++qt)
    #pragma unroll
    for (int hh = 0; hh < 2; ++hh)
      qf[qt][hh] = *(const short8*)(qg + (size_t)(tw + (qt << 4) + l15)*64 + (hh << 5) + (quad << 3));

  f32x4 o_acc[2][4];
  #pragma unroll
  for (int qt = 0; qt < 2; ++qt)
    #pragma unroll
    for (int ct = 0; ct < 4; ++ct) o_acc[qt][ct] = (f32x4){0.f,0.f,0.f,0.f};
  float m_[2] = {-1e30f, -1e30f}, l_[2] = {0.f, 0.f};

  auto loadK = [&](int s0, short8 (&ka)[4][2]){
    #pragma unroll
    for (int mt = 0; mt < 4; ++mt)
      #pragma unroll
      for (int h = 0; h < 2; ++h)
        ka[mt][h] = *(const short8*)(kg + (size_t)(s0 + (mt << 4) + l15)*64 + (h << 5) + (quad << 3));
  };

  auto body = [&](int st, short8 (&kaC)[4][2], short8 (&kaN)[4][2]){
    int s0 = st << 6;
    // V fragments for this iter (consumed after softmax, ~400 cyc later)
    short8 vb[4][2];
    #pragma unroll
    for (int ct = 0; ct < 4; ++ct)
      #pragma unroll
      for (int h = 0; h < 2; ++h)
        vb[ct][h] = *(const short8*)(vg + (size_t)((ct << 4) + l15)*TT + s0 + (h << 5) + (quad << 3));
    // prefetch next iter's K fragments (wrap at 63 -> in-bounds, unused)
    loadK(((st + 1) & 63) << 6, kaN);
    // S^T tiles
    f32x4 sv[4][2];
    #pragma unroll
    for (int mt = 0; mt < 4; ++mt)
      #pragma unroll
      for (int qt = 0; qt < 2; ++qt){
        f32x4 z = (f32x4){0.f,0.f,0.f,0.f};
        z = __builtin_amdgcn_mfma_f32_16x16x32_bf16(kaC[mt][0], qf[qt][0], z, 0, 0, 0);
        z = __builtin_amdgcn_mfma_f32_16x16x32_bf16(kaC[mt][1], qf[qt][1], z, 0, 0, 0);
        sv[mt][qt] = z;
      }
    // online softmax per q-tile (col t = l15; s spans regs+quads)
    float alpha[2];
    #pragma unroll
    for (int qt = 0; qt < 2; ++qt){
      float rm = -1e30f;
      #pragma unroll
      for (int mt = 0; mt < 4; ++mt)
        #pragma unroll
        for (int r = 0; r < 4; ++r) rm = fmaxf(rm, sv[mt][qt][r]);
      rm = fmaxf(rm, __shfl_xor(rm, 16));
      rm = fmaxf(rm, __shfl_xor(rm, 32));
      float mnew = fmaxf(m_[qt], rm);
      alpha[qt] = exp2f(m_[qt] - mnew);
      float rs = 0.f;
      #pragma unroll
      for (int mt = 0; mt < 4; ++mt){
        float p0 = exp2f(sv[mt][qt][0] - mnew);
        float p1 = exp2f(sv[mt][qt][1] - mnew);
        float p2 = exp2f(sv[mt][qt][2] - mnew);
        float p3 = exp2f(sv[mt][qt][3] - mnew);
        rs += (p0 + p1) + (p2 + p3);
        ushort4 pk; pk.x = f2bf_t(p0); pk.y = f2bf_t(p1); pk.z = f2bf_t(p2); pk.w = f2bf_t(p3);
        *(ushort4*)&p_lds[(w << 5) + (qt << 4) + l15][(mt << 4) + (quad << 2)] = pk;
      }
      rs += __shfl_xor(rs, 16);
      rs += __shfl_xor(rs, 32);
      l_[qt] = l_[qt]*alpha[qt] + rs;
      m_[qt] = mnew;
    }
    // rescale O (alpha uniform across quads; broadcast per D-row t)
    #pragma unroll
    for (int qt = 0; qt < 2; ++qt)
      #pragma unroll
      for (int r = 0; r < 4; ++r){
        float ar = __shfl(alpha[qt], (quad << 2) + r);
        #pragma unroll
        for (int ct = 0; ct < 4; ++ct) o_acc[qt][ct][r] *= ar;
      }
    // PV (pa from wave-private LDS; same-wave RAW -> lgkmcnt only, no barrier)
    short8 pa[2][2];
    #pragma unroll
    for (int qt = 0; qt < 2; ++qt){
      pa[qt][0] = *(const short8*)&p_lds[(w << 5) + (qt << 4) + l15][quad << 3];
      pa[qt][1] = *(const short8*)&p_lds[(w << 5) + (qt << 4) + l15][32 + (quad << 3)];
    }
    #pragma unroll
    for (int ct = 0; ct < 4; ++ct)
      #pragma unroll
      for (int qt = 0; qt < 2; ++qt){
        o_acc[qt][ct] = __builtin_amdgcn_mfma_f32_16x16x32_bf16(pa[qt][0], vb[ct][0], o_acc[qt][ct], 0, 0, 0);
        o_acc[qt][ct] = __builtin_amdgcn_mfma_f32_16x16x32_bf16(pa[qt][1], vb[ct][1], o_acc[qt][ct], 0, 0, 0);
      }
  };

  short8 kaA[4][2], kaB[4][2];
  loadK(0, kaA);
  for (int st2 = 0; st2 < 32; ++st2){
    body(2*st2,     kaA, kaB);
    body(2*st2 + 1, kaB, kaA);
  }

  // epilogue: normalize, O -> p_lds[t][c], coalesced store to aT [b][t][256]
  #pragma unroll
  for (int qt = 0; qt < 2; ++qt)
    #pragma unroll
    for (int r = 0; r < 4; ++r){
      float lr = __shfl(l_[qt], (quad << 2) + r);
      float ir = 1.f / lr;
      #pragma unroll
      for (int ct = 0; ct < 4; ++ct)
        p_lds[(w << 5) + (qt << 4) + (quad << 2) + r][(ct << 4) + l15] = f2bf(o_acc[qt][ct][r] * ir);
    }
  __syncthreads();
  size_t abase = ((size_t)(bh >> 2)*TT + t0)*256 + (size_t)(bh & 3)*64;
  #pragma unroll
  for (int pass = 0; pass < 4; ++pass){
    int chunk = (pass << 8) + tid;
    int row = chunk >> 3, c8 = (chunk & 7) << 3;
    *(uint4*)(aT + abase + (size_t)row*256 + c8) = *(const uint4*)&p_lds[row][c8];
  }
}

// ---------------- Kernel 5: proj GEMM (bf16 MFMA) + bias + residual ---------
// grid (64 t, 2 og, 4 b); wave owns 2 strips of 16 o.
__global__ __launch_bounds__(256)
void proj_mfma(const unsigned short* __restrict__ wb, const float* __restrict__ bias,
               const unsigned short* __restrict__ aT, const float* __restrict__ x,
               float* __restrict__ out){
  __shared__ unsigned short x_lds[64][72];
  int tid = threadIdx.x;
  int w = tid >> 6, lane = tid & 63, quad = lane >> 4, l15 = lane & 15;
  int t0 = blockIdx.x << 6, og = blockIdx.y, b = blockIdx.z;
  int o0 = og << 7;
  const unsigned short* xb = aT + (size_t)b * TT * 256;
  const unsigned short* wrow0 = wb + (size_t)(o0 + (w << 4) + l15) * 256;
  const unsigned short* wrow1 = wrow0 + (size_t)64 * 256;
  f32x4 acc[2][4];
  #pragma unroll
  for (int s = 0; s < 2; ++s)
    #pragma unroll
    for (int nt = 0; nt < 4; ++nt) acc[s][nt] = (f32x4){0.f,0.f,0.f,0.f};
  for (int ks = 0; ks < 4; ++ks){
    int k0 = ks << 6;
    __syncthreads();
    #pragma unroll
    for (int pass = 0; pass < 2; ++pass){
      int chunk = (pass << 8) + tid;
      int row = chunk >> 3, c8 = (chunk & 7) << 3;
      *(uint4*)&x_lds[row][c8] = *(const uint4*)(xb + (size_t)(t0 + row)*256 + k0 + c8);
    }
    __syncthreads();
    short8 wa[2][2];
    wa[0][0] = *(const short8*)(wrow0 + k0 + (quad << 3));
    wa[0][1] = *(const short8*)(wrow0 + k0 + 32 + (quad << 3));
    wa[1][0] = *(const short8*)(wrow1 + k0 + (quad << 3));
    wa[1][1] = *(const short8*)(wrow1 + k0 + 32 + (quad << 3));
    #pragma unroll
    for (int nt = 0; nt < 4; ++nt){
      short8 xb0 = *(const short8*)&x_lds[(nt << 4) + l15][quad << 3];
      short8 xb1 = *(const short8*)&x_lds[(nt << 4) + l15][32 + (quad << 3)];
      #pragma unroll
      for (int s = 0; s < 2; ++s){
        acc[s][nt] = __builtin_amdgcn_mfma_f32_16x16x32_bf16(wa[s][0], xb0, acc[s][nt], 0, 0, 0);
        acc[s][nt] = __builtin_amdgcn_mfma_f32_16x16x32_bf16(wa[s][1], xb1, acc[s][nt], 0, 0, 0);
      }
    }
  }
  #pragma unroll
  for (int s = 0; s < 2; ++s)
    #pragma unroll
    for (int r = 0; r < 4; ++r){
      int o = o0 + (s << 6) + (w << 4) + (quad << 2) + r;
      float bsv = bias[o];
      #pragma unroll
      for (int nt = 0; nt < 4; ++nt){
        size_t idx = ((size_t)(b*CCH + o))*TT + t0 + (nt << 4) + l15;
        out[idx] = acc[s][nt][r] + bsv + x[idx];
      }
    }
}

extern "C" void kernel_launch(void* const* d_in, const int* in_sizes, int n_in,
                              void* d_out, int out_size, void* d_ws, size_t ws_size,
                              hipStream_t stream){
  const float* x      = (const float*)d_in[0];
  const float* gn_w   = (const float*)d_in[1];
  const float* gn_b   = (const float*)d_in[2];
  const float* qkv_w  = (const float*)d_in[3];
  const float* qkv_b  = (const float*)d_in[4];
  const float* proj_w = (const float*)d_in[5];
  const float* proj_b = (const float*)d_in[6];
  float* out = (float*)d_out;

  float* sums = (float*)d_ws;
  unsigned short* wq_bf = (unsigned short*)(sums + 1024);
  unsigned short* wp_bf = wq_bf + (size_t)768*256;
  unsigned short* xnT   = wp_bf + (size_t)256*256;
  unsigned short* qT    = xnT + (size_t)4*TT*256;
  unsigned short* kT    = qT  + (size_t)16*TT*64;
  unsigned short* vO    = kT  + (size_t)16*TT*64;
  unsigned short* aT    = vO  + (size_t)16*64*TT;

  hipMemsetAsync(sums, 0, 1024*sizeof(float), stream);
  wconv<<<192, 256, 0, stream>>>(qkv_w, wq_bf);
  wconv<<<64, 256, 0, stream>>>(proj_w, wp_bf);
  gn_stats_part<<<512, 256, 0, stream>>>(x, sums);
  gn_apply_t<<<dim3(64, 4, 4), 256, 0, stream>>>(x, gn_w, gn_b, sums, xnT);
  qkv_mfma<<<dim3(64, 6, 4), 256, 0, stream>>>(wq_bf, qkv_b, xnT, qT, kT, vO);
  attn3<<<512, 256, 0, stream>>>(qT, kT, vO, aT);
  proj_mfma<<<dim3(64, 2, 4), 256, 0, stream>>>(wp_bf, proj_b, aT, x, out);
}

// Round 6
// 273.229 us; speedup vs baseline: 1.3005x; 1.3005x over previous
//
#include <hip/hip_runtime.h>
#include <cstdint>
#include <cstddef>

#define TT 4096   // T = H*W
#define CCH 256   // C

typedef __attribute__((ext_vector_type(8))) short short8;
typedef __attribute__((ext_vector_type(4))) float f32x4;

__device__ __forceinline__ float bf2f(unsigned int u){
  union { unsigned int i; float f; } v; v.i = u << 16; return v.f;
}
__device__ __forceinline__ unsigned short f2bf(float f){      // RNE
  unsigned int x = __float_as_uint(f);
  x += 0x7fffu + ((x >> 16) & 1u);
  return (unsigned short)(x >> 16);
}
__device__ __forceinline__ unsigned short f2bf_t(float f){    // truncate (p in [0,1])
  return (unsigned short)(__float_as_uint(f) >> 16);
}

// ---------------- Kernel 0: f32 -> bf16 weight convert ----------------------
__global__ __launch_bounds__(256)
void wconv(const float* __restrict__ src, unsigned short* __restrict__ dst){
  int i = blockIdx.x * 256 + threadIdx.x;
  float4 u = *(const float4*)(src + (size_t)i * 4);
  ushort4 r; r.x = f2bf(u.x); r.y = f2bf(u.y); r.z = f2bf(u.z); r.w = f2bf(u.w);
  *(ushort4*)(dst + (size_t)i * 4) = r;
}

// ---------------- Kernel 1: GroupNorm partial sums (atomic) -----------------
__global__ __launch_bounds__(256)
void gn_stats_part(const float* __restrict__ x, float* __restrict__ sums){
  int sg = blockIdx.x >> 2, part = blockIdx.x & 3;
  const float4* p = (const float4*)(x + (size_t)sg * 32768 + (size_t)part * 8192);
  int tid = threadIdx.x;
  float s = 0.f, sq = 0.f;
  #pragma unroll
  for (int it = 0; it < 8; ++it){
    float4 u = p[it * 256 + tid];
    s  += u.x + u.y + u.z + u.w;
    sq += u.x*u.x + u.y*u.y + u.z*u.z + u.w*u.w;
  }
  #pragma unroll
  for (int off = 32; off >= 1; off >>= 1){
    s  += __shfl_down(s, off);
    sq += __shfl_down(sq, off);
  }
  __shared__ float ls[4], lq[4];
  int w_ = tid >> 6, lane = tid & 63;
  if (lane == 0){ ls[w_] = s; lq[w_] = sq; }
  __syncthreads();
  if (tid == 0){
    atomicAdd(&sums[2*sg],   ls[0]+ls[1]+ls[2]+ls[3]);
    atomicAdd(&sums[2*sg+1], lq[0]+lq[1]+lq[2]+lq[3]);
  }
}

// ---------------- Kernel 2: GN apply + transpose -> xnT bf16 [b][t][256] ----
__global__ __launch_bounds__(256)
void gn_apply_t(const float* __restrict__ x, const float* __restrict__ gw,
                const float* __restrict__ gb, const float* __restrict__ sums,
                unsigned short* __restrict__ xnT){
  __shared__ unsigned short t_lds[64][72];
  int tid = threadIdx.x;
  int t0 = blockIdx.x << 6, c0 = blockIdx.y << 6, b = blockIdx.z;
  int t4 = (tid & 15) << 2, cr = tid >> 4;
  #pragma unroll
  for (int pass = 0; pass < 4; ++pass){
    int cl = (pass << 4) + cr;
    int c = c0 + cl;
    int sg = (b << 5) | (c >> 3);
    float s = sums[2*sg], q = sums[2*sg+1];
    float mean = s * (1.f/32768.f);
    float var  = q * (1.f/32768.f) - mean*mean;
    float rstd = rsqrtf(var + 1e-5f);
    float sc = gw[c] * rstd;
    float sh = gb[c] - mean * sc;
    float4 u = *(const float4*)(x + ((size_t)(b*CCH + c))*TT + t0 + t4);
    t_lds[t4+0][cl] = f2bf(u.x*sc + sh);
    t_lds[t4+1][cl] = f2bf(u.y*sc + sh);
    t_lds[t4+2][cl] = f2bf(u.z*sc + sh);
    t_lds[t4+3][cl] = f2bf(u.w*sc + sh);
  }
  __syncthreads();
  #pragma unroll
  for (int pass = 0; pass < 2; ++pass){
    int chunk = (pass << 8) + tid;
    int row = chunk >> 3, c8 = (chunk & 7) << 3;
    *(uint4*)(xnT + ((size_t)b*TT + t0 + row)*256 + c0 + c8) = *(const uint4*)&t_lds[row][c8];
  }
}

// ---------------- Kernel 3: QKV GEMM (bf16 MFMA) ----------------------------
__global__ __launch_bounds__(256)
void qkv_mfma(const unsigned short* __restrict__ wb, const float* __restrict__ bias,
              const unsigned short* __restrict__ xnT,
              unsigned short* __restrict__ qT, unsigned short* __restrict__ kT,
              unsigned short* __restrict__ vO){
  __shared__ unsigned short x_lds[64][72];
  int tid = threadIdx.x;
  int w = tid >> 6, lane = tid & 63, quad = lane >> 4, l15 = lane & 15;
  int t0 = blockIdx.x << 6, o0 = blockIdx.y << 6, b = blockIdx.z;
  const unsigned short* xb = xnT + (size_t)b * TT * 256;
  const unsigned short* wrow = wb + (size_t)(o0 + (w << 4) + l15) * 256;
  f32x4 acc[4];
  #pragma unroll
  for (int nt = 0; nt < 4; ++nt) acc[nt] = (f32x4){0.f,0.f,0.f,0.f};
  for (int ks = 0; ks < 4; ++ks){
    int k0 = ks << 6;
    __syncthreads();
    #pragma unroll
    for (int pass = 0; pass < 2; ++pass){
      int chunk = (pass << 8) + tid;
      int row = chunk >> 3, c8 = (chunk & 7) << 3;
      *(uint4*)&x_lds[row][c8] = *(const uint4*)(xb + (size_t)(t0 + row)*256 + k0 + c8);
    }
    __syncthreads();
    short8 wa0 = *(const short8*)(wrow + k0 + (quad << 3));
    short8 wa1 = *(const short8*)(wrow + k0 + 32 + (quad << 3));
    #pragma unroll
    for (int nt = 0; nt < 4; ++nt){
      short8 xb0 = *(const short8*)&x_lds[(nt << 4) + l15][quad << 3];
      short8 xb1 = *(const short8*)&x_lds[(nt << 4) + l15][32 + (quad << 3)];
      acc[nt] = __builtin_amdgcn_mfma_f32_16x16x32_bf16(wa0, xb0, acc[nt], 0, 0, 0);
      acc[nt] = __builtin_amdgcn_mfma_f32_16x16x32_bf16(wa1, xb1, acc[nt], 0, 0, 0);
    }
  }
  int sec = blockIdx.y >> 2, h = blockIdx.y & 3, bh = (b << 2) | h;
  float bs[4];
  #pragma unroll
  for (int r = 0; r < 4; ++r) bs[r] = bias[o0 + (w << 4) + (quad << 2) + r];
  __syncthreads();
  if (sec < 2){
    float qsc = (sec == 0) ? 0.125f * 1.44269504f : 1.0f;
    #pragma unroll
    for (int nt = 0; nt < 4; ++nt){
      ushort4 pk;
      pk.x = f2bf((acc[nt][0] + bs[0]) * qsc);
      pk.y = f2bf((acc[nt][1] + bs[1]) * qsc);
      pk.z = f2bf((acc[nt][2] + bs[2]) * qsc);
      pk.w = f2bf((acc[nt][3] + bs[3]) * qsc);
      *(ushort4*)&x_lds[(nt << 4) + l15][(w << 4) + (quad << 2)] = pk;
    }
    __syncthreads();
    unsigned short* dst = (sec == 0) ? qT : kT;
    #pragma unroll
    for (int pass = 0; pass < 2; ++pass){
      int chunk = (pass << 8) + tid;
      int row = chunk >> 3, c8 = (chunk & 7) << 3;
      *(uint4*)(dst + ((size_t)bh*TT + t0 + row)*64 + c8) = *(const uint4*)&x_lds[row][c8];
    }
  } else {
    #pragma unroll
    for (int nt = 0; nt < 4; ++nt)
      #pragma unroll
      for (int r = 0; r < 4; ++r)
        x_lds[(w << 4) + (quad << 2) + r][(nt << 4) + l15] = f2bf(acc[nt][r] + bs[r]);
    __syncthreads();
    #pragma unroll
    for (int pass = 0; pass < 2; ++pass){
      int chunk = (pass << 8) + tid;
      int row = chunk >> 3, c8 = (chunk & 7) << 3;
      *(uint4*)(vO + ((size_t)bh*64 + row)*TT + t0 + c8) = *(const uint4*)&x_lds[row][c8];
    }
  }
}

// ---------------- Kernel 4: flash attention, 64-q blocks + reg prefetch -----
// block = (bh, 64 q); 4 waves x 16 q. S^T orientation. K/V tile staged in LDS;
// next tile's global loads issued right after this tile's ds_writes so vmcnt
// latency overlaps compute. 2 barriers/iter but no global wait inside them.
__global__ __launch_bounds__(256, 4)
void attn4(const unsigned short* __restrict__ qT, const unsigned short* __restrict__ kT,
           const unsigned short* __restrict__ vO, unsigned short* __restrict__ aT){
  __shared__ __align__(16) unsigned short k_lds[64][72];   // [s][c]
  __shared__ __align__(16) unsigned short v_lds[64][72];   // [c][s]
  __shared__ __align__(16) unsigned short p_lds[64][72];   // [t][s]; reused as O[t][c]
  int tid = threadIdx.x;
  int w = tid >> 6, lane = tid & 63, quad = lane >> 4, l15 = lane & 15;
  int qt6 = blockIdx.x & 63, bh = blockIdx.x >> 6;
  int t0 = qt6 << 6;
  const unsigned short* qg = qT + (size_t)bh * TT * 64;
  const unsigned short* kg = kT + (size_t)bh * TT * 64;
  const unsigned short* vg = vO + (size_t)bh * 64 * TT;
  int tw = t0 + (w << 4);

  // staging addresses (per thread, 2 chunks of 16B per matrix)
  int row0 = tid >> 3,        c80 = (tid & 7) << 3;          // chunk 0
  int row1 = (tid + 256) >> 3, c81 = c80;                    // chunk 1 (row0+32)
  row1 = row0 + 32;

  short8 qf[2];
  qf[0] = *(const short8*)(qg + (size_t)(tw + l15)*64 + (quad << 3));
  qf[1] = *(const short8*)(qg + (size_t)(tw + l15)*64 + 32 + (quad << 3));

  f32x4 o_acc[4];
  #pragma unroll
  for (int ct = 0; ct < 4; ++ct) o_acc[ct] = (f32x4){0.f,0.f,0.f,0.f};
  float m_ = -1e30f, l_ = 0.f;

  // preload tile 0 into registers
  uint4 kr0 = *(const uint4*)(kg + (size_t)row0*64 + c80);
  uint4 kr1 = *(const uint4*)(kg + (size_t)row1*64 + c81);
  uint4 vr0 = *(const uint4*)(vg + (size_t)row0*TT + c80);
  uint4 vr1 = *(const uint4*)(vg + (size_t)row1*TT + c81);

  for (int st = 0; st < 64; ++st){
    __syncthreads();                 // prev iter's fragment reads done
    *(uint4*)&k_lds[row0][c80] = kr0;
    *(uint4*)&k_lds[row1][c81] = kr1;
    *(uint4*)&v_lds[row0][c80] = vr0;
    *(uint4*)&v_lds[row1][c81] = vr1;
    if (st < 63){                    // issue next tile's loads (overlap compute)
      int sn = (st + 1) << 6;
      kr0 = *(const uint4*)(kg + (size_t)(sn + row0)*64 + c80);
      kr1 = *(const uint4*)(kg + (size_t)(sn + row1)*64 + c81);
      vr0 = *(const uint4*)(vg + (size_t)row0*TT + sn + c80);
      vr1 = *(const uint4*)(vg + (size_t)row1*TT + sn + c81);
    }
    __syncthreads();                 // tile visible
    // S^T tiles: rows s = mt*16+quad*4+r, col t = l15
    f32x4 sv[4];
    #pragma unroll
    for (int mt = 0; mt < 4; ++mt){
      short8 ka0 = *(const short8*)&k_lds[(mt << 4) + l15][quad << 3];
      short8 ka1 = *(const short8*)&k_lds[(mt << 4) + l15][32 + (quad << 3)];
      f32x4 z = (f32x4){0.f,0.f,0.f,0.f};
      z = __builtin_amdgcn_mfma_f32_16x16x32_bf16(ka0, qf[0], z, 0, 0, 0);
      z = __builtin_amdgcn_mfma_f32_16x16x32_bf16(ka1, qf[1], z, 0, 0, 0);
      sv[mt] = z;
    }
    // online softmax over s (16 in-lane + 2 cross-quad shfl)
    float rm = -1e30f;
    #pragma unroll
    for (int mt = 0; mt < 4; ++mt)
      #pragma unroll
      for (int r = 0; r < 4; ++r) rm = fmaxf(rm, sv[mt][r]);
    rm = fmaxf(rm, __shfl_xor(rm, 16));
    rm = fmaxf(rm, __shfl_xor(rm, 32));
    float mnew = fmaxf(m_, rm);
    float alpha = exp2f(m_ - mnew);
    float rs = 0.f;
    #pragma unroll
    for (int mt = 0; mt < 4; ++mt){
      float p0 = exp2f(sv[mt][0] - mnew);
      float p1 = exp2f(sv[mt][1] - mnew);
      float p2 = exp2f(sv[mt][2] - mnew);
      float p3 = exp2f(sv[mt][3] - mnew);
      rs += (p0 + p1) + (p2 + p3);
      ushort4 pk; pk.x = f2bf_t(p0); pk.y = f2bf_t(p1); pk.z = f2bf_t(p2); pk.w = f2bf_t(p3);
      *(ushort4*)&p_lds[(w << 4) + l15][(mt << 4) + (quad << 2)] = pk;
    }
    rs += __shfl_xor(rs, 16);
    rs += __shfl_xor(rs, 32);
    l_ = l_*alpha + rs;
    m_ = mnew;
    // rescale O rows (row t = quad*4+r; alpha lives at lane t)
    #pragma unroll
    for (int r = 0; r < 4; ++r){
      float ar = __shfl(alpha, (quad << 2) + r);
      #pragma unroll
      for (int ct = 0; ct < 4; ++ct) o_acc[ct][r] *= ar;
    }
    // PV (pa wave-private rows: same-wave RAW, no barrier)
    short8 pa0 = *(const short8*)&p_lds[(w << 4) + l15][quad << 3];
    short8 pa1 = *(const short8*)&p_lds[(w << 4) + l15][32 + (quad << 3)];
    #pragma unroll
    for (int ct = 0; ct < 4; ++ct){
      short8 vb0 = *(const short8*)&v_lds[(ct << 4) + l15][quad << 3];
      short8 vb1 = *(const short8*)&v_lds[(ct << 4) + l15][32 + (quad << 3)];
      o_acc[ct] = __builtin_amdgcn_mfma_f32_16x16x32_bf16(pa0, vb0, o_acc[ct], 0, 0, 0);
      o_acc[ct] = __builtin_amdgcn_mfma_f32_16x16x32_bf16(pa1, vb1, o_acc[ct], 0, 0, 0);
    }
  }
  // epilogue: normalize, O -> p_lds[t][c], coalesced store to aT [b][t][256]
  __syncthreads();                   // k/v/p fragment reads done; reuse p_lds
  #pragma unroll
  for (int r = 0; r < 4; ++r){
    float lr = __shfl(l_, (quad << 2) + r);
    float ir = 1.f / lr;
    #pragma unroll
    for (int ct = 0; ct < 4; ++ct)
      p_lds[(w << 4) + (quad << 2) + r][(ct << 4) + l15] = f2bf(o_acc[ct][r] * ir);
  }
  __syncthreads();
  size_t abase = ((size_t)(bh >> 2)*TT + t0)*256 + (size_t)(bh & 3)*64;
  #pragma unroll
  for (int pass = 0; pass < 2; ++pass){
    int chunk = (pass << 8) + tid;
    int row = chunk >> 3, c8 = (chunk & 7) << 3;
    *(uint4*)(aT + abase + (size_t)row*256 + c8) = *(const uint4*)&p_lds[row][c8];
  }
}

// ---------------- Kernel 5: proj GEMM (bf16 MFMA) + bias + residual ---------
__global__ __launch_bounds__(256)
void proj_mfma(const unsigned short* __restrict__ wb, const float* __restrict__ bias,
               const unsigned short* __restrict__ aT, const float* __restrict__ x,
               float* __restrict__ out){
  __shared__ unsigned short x_lds[64][72];
  int tid = threadIdx.x;
  int w = tid >> 6, lane = tid & 63, quad = lane >> 4, l15 = lane & 15;
  int t0 = blockIdx.x << 6, o0 = blockIdx.y << 6, b = blockIdx.z;
  const unsigned short* xb = aT + (size_t)b * TT * 256;
  const unsigned short* wrow = wb + (size_t)(o0 + (w << 4) + l15) * 256;
  f32x4 acc[4];
  #pragma unroll
  for (int nt = 0; nt < 4; ++nt) acc[nt] = (f32x4){0.f,0.f,0.f,0.f};
  for (int ks = 0; ks < 4; ++ks){
    int k0 = ks << 6;
    __syncthreads();
    #pragma unroll
    for (int pass = 0; pass < 2; ++pass){
      int chunk = (pass << 8) + tid;
      int row = chunk >> 3, c8 = (chunk & 7) << 3;
      *(uint4*)&x_lds[row][c8] = *(const uint4*)(xb + (size_t)(t0 + row)*256 + k0 + c8);
    }
    __syncthreads();
    short8 wa0 = *(const short8*)(wrow + k0 + (quad << 3));
    short8 wa1 = *(const short8*)(wrow + k0 + 32 + (quad << 3));
    #pragma unroll
    for (int nt = 0; nt < 4; ++nt){
      short8 xb0 = *(const short8*)&x_lds[(nt << 4) + l15][quad << 3];
      short8 xb1 = *(const short8*)&x_lds[(nt << 4) + l15][32 + (quad << 3)];
      acc[nt] = __builtin_amdgcn_mfma_f32_16x16x32_bf16(wa0, xb0, acc[nt], 0, 0, 0);
      acc[nt] = __builtin_amdgcn_mfma_f32_16x16x32_bf16(wa1, xb1, acc[nt], 0, 0, 0);
    }
  }
  #pragma unroll
  for (int r = 0; r < 4; ++r){
    int o = o0 + (w << 4) + (quad << 2) + r;
    float bsv = bias[o];
    #pragma unroll
    for (int nt = 0; nt < 4; ++nt){
      size_t idx = ((size_t)(b*CCH + o))*TT + t0 + (nt << 4) + l15;
      out[idx] = acc[nt][r] + bsv + x[idx];
    }
  }
}

extern "C" void kernel_launch(void* const* d_in, const int* in_sizes, int n_in,
                              void* d_out, int out_size, void* d_ws, size_t ws_size,
                              hipStream_t stream){
  const float* x      = (const float*)d_in[0];
  const float* gn_w   = (const float*)d_in[1];
  const float* gn_b   = (const float*)d_in[2];
  const float* qkv_w  = (const float*)d_in[3];
  const float* qkv_b  = (const float*)d_in[4];
  const float* proj_w = (const float*)d_in[5];
  const float* proj_b = (const float*)d_in[6];
  float* out = (float*)d_out;

  float* sums = (float*)d_ws;
  unsigned short* wq_bf = (unsigned short*)(sums + 1024);
  unsigned short* wp_bf = wq_bf + (size_t)768*256;
  unsigned short* xnT   = wp_bf + (size_t)256*256;
  unsigned short* qT    = xnT + (size_t)4*TT*256;
  unsigned short* kT    = qT  + (size_t)16*TT*64;
  unsigned short* vO    = kT  + (size_t)16*TT*64;
  unsigned short* aT    = vO  + (size_t)16*64*TT;

  hipMemsetAsync(sums, 0, 1024*sizeof(float), stream);
  wconv<<<192, 256, 0, stream>>>(qkv_w, wq_bf);
  wconv<<<64, 256, 0, stream>>>(proj_w, wp_bf);
  gn_stats_part<<<512, 256, 0, stream>>>(x, sums);
  gn_apply_t<<<dim3(64, 4, 4), 256, 0, stream>>>(x, gn_w, gn_b, sums, xnT);
  qkv_mfma<<<dim3(64, 12, 4), 256, 0, stream>>>(wq_bf, qkv_b, xnT, qT, kT, vO);
  attn4<<<1024, 256, 0, stream>>>(qT, kT, vO, aT);
  proj_mfma<<<dim3(64, 4, 4), 256, 0, stream>>>(wp_bf, proj_b, aT, x, out);
}

// Round 7
// 257.248 us; speedup vs baseline: 1.3813x; 1.0621x over previous
//
#include <hip/hip_runtime.h>
#include <cstdint>
#include <cstddef>

#define TT 4096   // T = H*W
#define CCH 256   // C

typedef __attribute__((ext_vector_type(8))) short short8;
typedef __attribute__((ext_vector_type(4))) float f32x4;

__device__ __forceinline__ float bf2f(unsigned int u){
  union { unsigned int i; float f; } v; v.i = u << 16; return v.f;
}
__device__ __forceinline__ unsigned short f2bf(float f){      // RNE
  unsigned int x = __float_as_uint(f);
  x += 0x7fffu + ((x >> 16) & 1u);
  return (unsigned short)(x >> 16);
}
__device__ __forceinline__ unsigned short f2bf_t(float f){    // truncate (p in [0,1])
  return (unsigned short)(__float_as_uint(f) >> 16);
}

// ---------------- Kernel 1: fused weight-convert + GroupNorm stats ----------
// blocks 0..191: qkv_w f32->bf16; 192..255: proj_w; 256..383: GN stats
// (one block per (b,group), writes mean/rstd directly).
__global__ __launch_bounds__(256)
void wconv_gn(const float* __restrict__ qkv_w, const float* __restrict__ proj_w,
              const float* __restrict__ x,
              unsigned short* __restrict__ wq_bf, unsigned short* __restrict__ wp_bf,
              float* __restrict__ stats){
  int bid = blockIdx.x, tid = threadIdx.x;
  if (bid < 256){
    const float* src = (bid < 192) ? qkv_w : proj_w;
    unsigned short* dst = (bid < 192) ? wq_bf : wp_bf;
    int i = (bid < 192 ? bid : bid - 192) * 256 + tid;
    float4 u = *(const float4*)(src + (size_t)i * 4);
    ushort4 r; r.x = f2bf(u.x); r.y = f2bf(u.y); r.z = f2bf(u.z); r.w = f2bf(u.w);
    *(ushort4*)(dst + (size_t)i * 4) = r;
    return;
  }
  int sg = bid - 256;                         // b*32+g
  const float4* p = (const float4*)(x + (size_t)sg * 32768);
  float s = 0.f, sq = 0.f;
  #pragma unroll
  for (int it = 0; it < 32; ++it){
    float4 u = p[it * 256 + tid];
    s  += u.x + u.y + u.z + u.w;
    sq += u.x*u.x + u.y*u.y + u.z*u.z + u.w*u.w;
  }
  #pragma unroll
  for (int off = 32; off >= 1; off >>= 1){
    s  += __shfl_down(s, off);
    sq += __shfl_down(sq, off);
  }
  __shared__ float ls[4], lq[4];
  int w_ = tid >> 6, lane = tid & 63;
  if (lane == 0){ ls[w_] = s; lq[w_] = sq; }
  __syncthreads();
  if (tid == 0){
    float S = ls[0]+ls[1]+ls[2]+ls[3];
    float Q = lq[0]+lq[1]+lq[2]+lq[3];
    float mean = S * (1.f/32768.f);
    float var  = Q * (1.f/32768.f) - mean*mean;
    stats[2*sg]   = mean;
    stats[2*sg+1] = rsqrtf(var + 1e-5f);
  }
}

// ---------------- Kernel 2: GN apply + transpose -> xnT bf16 [b][t][256] ----
__global__ __launch_bounds__(256)
void gn_apply_t(const float* __restrict__ x, const float* __restrict__ gw,
                const float* __restrict__ gb, const float* __restrict__ stats,
                unsigned short* __restrict__ xnT){
  __shared__ unsigned short t_lds[64][72];
  int tid = threadIdx.x;
  int t0 = blockIdx.x << 6, c0 = blockIdx.y << 6, b = blockIdx.z;
  int t4 = (tid & 15) << 2, cr = tid >> 4;
  #pragma unroll
  for (int pass = 0; pass < 4; ++pass){
    int cl = (pass << 4) + cr;
    int c = c0 + cl;
    int sg = (b << 5) | (c >> 3);
    float mean = stats[2*sg], rstd = stats[2*sg+1];
    float sc = gw[c] * rstd;
    float sh = gb[c] - mean * sc;
    float4 u = *(const float4*)(x + ((size_t)(b*CCH + c))*TT + t0 + t4);
    t_lds[t4+0][cl] = f2bf(u.x*sc + sh);
    t_lds[t4+1][cl] = f2bf(u.y*sc + sh);
    t_lds[t4+2][cl] = f2bf(u.z*sc + sh);
    t_lds[t4+3][cl] = f2bf(u.w*sc + sh);
  }
  __syncthreads();
  #pragma unroll
  for (int pass = 0; pass < 2; ++pass){
    int chunk = (pass << 8) + tid;
    int row = chunk >> 3, c8 = (chunk & 7) << 3;
    *(uint4*)(xnT + ((size_t)b*TT + t0 + row)*256 + c0 + c8) = *(const uint4*)&t_lds[row][c8];
  }
}

// ---------------- Kernel 3: QKV GEMM (bf16 MFMA) ----------------------------
__global__ __launch_bounds__(256)
void qkv_mfma(const unsigned short* __restrict__ wb, const float* __restrict__ bias,
              const unsigned short* __restrict__ xnT,
              unsigned short* __restrict__ qT, unsigned short* __restrict__ kT,
              unsigned short* __restrict__ vO){
  __shared__ unsigned short x_lds[64][72];
  int tid = threadIdx.x;
  int w = tid >> 6, lane = tid & 63, quad = lane >> 4, l15 = lane & 15;
  int t0 = blockIdx.x << 6, o0 = blockIdx.y << 6, b = blockIdx.z;
  const unsigned short* xb = xnT + (size_t)b * TT * 256;
  const unsigned short* wrow = wb + (size_t)(o0 + (w << 4) + l15) * 256;
  f32x4 acc[4];
  #pragma unroll
  for (int nt = 0; nt < 4; ++nt) acc[nt] = (f32x4){0.f,0.f,0.f,0.f};
  for (int ks = 0; ks < 4; ++ks){
    int k0 = ks << 6;
    __syncthreads();
    #pragma unroll
    for (int pass = 0; pass < 2; ++pass){
      int chunk = (pass << 8) + tid;
      int row = chunk >> 3, c8 = (chunk & 7) << 3;
      *(uint4*)&x_lds[row][c8] = *(const uint4*)(xb + (size_t)(t0 + row)*256 + k0 + c8);
    }
    __syncthreads();
    short8 wa0 = *(const short8*)(wrow + k0 + (quad << 3));
    short8 wa1 = *(const short8*)(wrow + k0 + 32 + (quad << 3));
    #pragma unroll
    for (int nt = 0; nt < 4; ++nt){
      short8 xb0 = *(const short8*)&x_lds[(nt << 4) + l15][quad << 3];
      short8 xb1 = *(const short8*)&x_lds[(nt << 4) + l15][32 + (quad << 3)];
      acc[nt] = __builtin_amdgcn_mfma_f32_16x16x32_bf16(wa0, xb0, acc[nt], 0, 0, 0);
      acc[nt] = __builtin_amdgcn_mfma_f32_16x16x32_bf16(wa1, xb1, acc[nt], 0, 0, 0);
    }
  }
  int sec = blockIdx.y >> 2, h = blockIdx.y & 3, bh = (b << 2) | h;
  float bs[4];
  #pragma unroll
  for (int r = 0; r < 4; ++r) bs[r] = bias[o0 + (w << 4) + (quad << 2) + r];
  __syncthreads();
  if (sec < 2){
    float qsc = (sec == 0) ? 0.125f * 1.44269504f : 1.0f;
    #pragma unroll
    for (int nt = 0; nt < 4; ++nt){
      ushort4 pk;
      pk.x = f2bf((acc[nt][0] + bs[0]) * qsc);
      pk.y = f2bf((acc[nt][1] + bs[1]) * qsc);
      pk.z = f2bf((acc[nt][2] + bs[2]) * qsc);
      pk.w = f2bf((acc[nt][3] + bs[3]) * qsc);
      *(ushort4*)&x_lds[(nt << 4) + l15][(w << 4) + (quad << 2)] = pk;
    }
    __syncthreads();
    unsigned short* dst = (sec == 0) ? qT : kT;
    #pragma unroll
    for (int pass = 0; pass < 2; ++pass){
      int chunk = (pass << 8) + tid;
      int row = chunk >> 3, c8 = (chunk & 7) << 3;
      *(uint4*)(dst + ((size_t)bh*TT + t0 + row)*64 + c8) = *(const uint4*)&x_lds[row][c8];
    }
  } else {
    #pragma unroll
    for (int nt = 0; nt < 4; ++nt)
      #pragma unroll
      for (int r = 0; r < 4; ++r)
        x_lds[(w << 4) + (quad << 2) + r][(nt << 4) + l15] = f2bf(acc[nt][r] + bs[r]);
    __syncthreads();
    #pragma unroll
    for (int pass = 0; pass < 2; ++pass){
      int chunk = (pass << 8) + tid;
      int row = chunk >> 3, c8 = (chunk & 7) << 3;
      *(uint4*)(vO + ((size_t)bh*64 + row)*TT + t0 + c8) = *(const uint4*)&x_lds[row][c8];
    }
  }
}

// ---------------- Kernel 4: flash attention, O-transposed PV ----------------
// block = (bh, 64 q); bh = blockIdx&15 -> all q-blocks of a bh on one XCD.
// S^T = K·Q^T (col t=l15). PV computes O^T = V·P^T (col t=l15) so alpha and
// 1/l apply IN-LANE (no broadcast shfl). K/V staged in LDS w/ reg prefetch.
__global__ __launch_bounds__(256, 4)
void attn5(const unsigned short* __restrict__ qT, const unsigned short* __restrict__ kT,
           const unsigned short* __restrict__ vO, unsigned short* __restrict__ aT){
  __shared__ __align__(16) unsigned short k_lds[64][72];   // [s][c]
  __shared__ __align__(16) unsigned short v_lds[64][72];   // [c][s]
  __shared__ __align__(16) unsigned short p_lds[64][72];   // [t][s]; reused as O[t][c]
  int tid = threadIdx.x;
  int w = tid >> 6, lane = tid & 63, quad = lane >> 4, l15 = lane & 15;
  int bh = blockIdx.x & 15, qt6 = blockIdx.x >> 4;         // XCD swizzle
  int t0 = qt6 << 6;
  const unsigned short* qg = qT + (size_t)bh * TT * 64;
  const unsigned short* kg = kT + (size_t)bh * TT * 64;
  const unsigned short* vg = vO + (size_t)bh * 64 * TT;
  int tw = t0 + (w << 4);

  int row0 = tid >> 3, c80 = (tid & 7) << 3;
  int row1 = row0 + 32, c81 = c80;

  short8 qf[2];
  qf[0] = *(const short8*)(qg + (size_t)(tw + l15)*64 + (quad << 3));
  qf[1] = *(const short8*)(qg + (size_t)(tw + l15)*64 + 32 + (quad << 3));

  f32x4 o_acc[4];                      // O^T tiles: row c=ct*16+quad*4+r, col t=l15
  #pragma unroll
  for (int ct = 0; ct < 4; ++ct) o_acc[ct] = (f32x4){0.f,0.f,0.f,0.f};
  float m_ = -1e30f, l_ = 0.f;         // per-t state, lives at lane l15 (all quads)

  uint4 kr0 = *(const uint4*)(kg + (size_t)row0*64 + c80);
  uint4 kr1 = *(const uint4*)(kg + (size_t)row1*64 + c81);
  uint4 vr0 = *(const uint4*)(vg + (size_t)row0*TT + c80);
  uint4 vr1 = *(const uint4*)(vg + (size_t)row1*TT + c81);

  for (int st = 0; st < 64; ++st){
    __syncthreads();
    *(uint4*)&k_lds[row0][c80] = kr0;
    *(uint4*)&k_lds[row1][c81] = kr1;
    *(uint4*)&v_lds[row0][c80] = vr0;
    *(uint4*)&v_lds[row1][c81] = vr1;
    if (st < 63){
      int sn = (st + 1) << 6;
      kr0 = *(const uint4*)(kg + (size_t)(sn + row0)*64 + c80);
      kr1 = *(const uint4*)(kg + (size_t)(sn + row1)*64 + c81);
      vr0 = *(const uint4*)(vg + (size_t)row0*TT + sn + c80);
      vr1 = *(const uint4*)(vg + (size_t)row1*TT + sn + c81);
    }
    __syncthreads();
    // S^T: rows s = mt*16+quad*4+r, col t = l15
    f32x4 sv[4];
    #pragma unroll
    for (int mt = 0; mt < 4; ++mt){
      short8 ka0 = *(const short8*)&k_lds[(mt << 4) + l15][quad << 3];
      short8 ka1 = *(const short8*)&k_lds[(mt << 4) + l15][32 + (quad << 3)];
      f32x4 z = (f32x4){0.f,0.f,0.f,0.f};
      z = __builtin_amdgcn_mfma_f32_16x16x32_bf16(ka0, qf[0], z, 0, 0, 0);
      z = __builtin_amdgcn_mfma_f32_16x16x32_bf16(ka1, qf[1], z, 0, 0, 0);
      sv[mt] = z;
    }
    // online softmax over s (in-lane + 2 cross-quad shfl)
    float rm = -1e30f;
    #pragma unroll
    for (int mt = 0; mt < 4; ++mt)
      #pragma unroll
      for (int r = 0; r < 4; ++r) rm = fmaxf(rm, sv[mt][r]);
    rm = fmaxf(rm, __shfl_xor(rm, 16));
    rm = fmaxf(rm, __shfl_xor(rm, 32));
    float mnew = fmaxf(m_, rm);
    float alpha = exp2f(m_ - mnew);
    float rs = 0.f;
    #pragma unroll
    for (int mt = 0; mt < 4; ++mt){
      float p0 = exp2f(sv[mt][0] - mnew);
      float p1 = exp2f(sv[mt][1] - mnew);
      float p2 = exp2f(sv[mt][2] - mnew);
      float p3 = exp2f(sv[mt][3] - mnew);
      rs += (p0 + p1) + (p2 + p3);
      ushort4 pk; pk.x = f2bf_t(p0); pk.y = f2bf_t(p1); pk.z = f2bf_t(p2); pk.w = f2bf_t(p3);
      *(ushort4*)&p_lds[(w << 4) + l15][(mt << 4) + (quad << 2)] = pk;
    }
    rs += __shfl_xor(rs, 16);
    rs += __shfl_xor(rs, 32);
    l_ = l_*alpha + rs;
    m_ = mnew;
    // rescale O^T in-lane (col t = l15 carries alpha)
    #pragma unroll
    for (int ct = 0; ct < 4; ++ct)
      #pragma unroll
      for (int r = 0; r < 4; ++r) o_acc[ct][r] *= alpha;
    // PV: O^T = V·P^T  (A = V[c][s] rows, B = P[t][s] rows; same reads as before)
    short8 pb0 = *(const short8*)&p_lds[(w << 4) + l15][quad << 3];
    short8 pb1 = *(const short8*)&p_lds[(w << 4) + l15][32 + (quad << 3)];
    #pragma unroll
    for (int ct = 0; ct < 4; ++ct){
      short8 va0 = *(const short8*)&v_lds[(ct << 4) + l15][quad << 3];
      short8 va1 = *(const short8*)&v_lds[(ct << 4) + l15][32 + (quad << 3)];
      o_acc[ct] = __builtin_amdgcn_mfma_f32_16x16x32_bf16(va0, pb0, o_acc[ct], 0, 0, 0);
      o_acc[ct] = __builtin_amdgcn_mfma_f32_16x16x32_bf16(va1, pb1, o_acc[ct], 0, 0, 0);
    }
  }
  // epilogue: normalize in-lane, O^T -> p_lds[t][c] (vector b64), store aT
  __syncthreads();
  float ir = 1.f / l_;
  #pragma unroll
  for (int ct = 0; ct < 4; ++ct){
    ushort4 ok;
    ok.x = f2bf(o_acc[ct][0] * ir);
    ok.y = f2bf(o_acc[ct][1] * ir);
    ok.z = f2bf(o_acc[ct][2] * ir);
    ok.w = f2bf(o_acc[ct][3] * ir);
    *(ushort4*)&p_lds[(w << 4) + l15][(ct << 4) + (quad << 2)] = ok;
  }
  __syncthreads();
  size_t abase = ((size_t)(bh >> 2)*TT + t0)*256 + (size_t)(bh & 3)*64;
  #pragma unroll
  for (int pass = 0; pass < 2; ++pass){
    int chunk = (pass << 8) + tid;
    int row = chunk >> 3, c8 = (chunk & 7) << 3;
    *(uint4*)(aT + abase + (size_t)row*256 + c8) = *(const uint4*)&p_lds[row][c8];
  }
}

// ---------------- Kernel 5: proj GEMM (bf16 MFMA) + bias + residual ---------
__global__ __launch_bounds__(256)
void proj_mfma(const unsigned short* __restrict__ wb, const float* __restrict__ bias,
               const unsigned short* __restrict__ aT, const float* __restrict__ x,
               float* __restrict__ out){
  __shared__ unsigned short x_lds[64][72];
  int tid = threadIdx.x;
  int w = tid >> 6, lane = tid & 63, quad = lane >> 4, l15 = lane & 15;
  int t0 = blockIdx.x << 6, o0 = blockIdx.y << 6, b = blockIdx.z;
  const unsigned short* xb = aT + (size_t)b * TT * 256;
  const unsigned short* wrow = wb + (size_t)(o0 + (w << 4) + l15) * 256;
  f32x4 acc[4];
  #pragma unroll
  for (int nt = 0; nt < 4; ++nt) acc[nt] = (f32x4){0.f,0.f,0.f,0.f};
  for (int ks = 0; ks < 4; ++ks){
    int k0 = ks << 6;
    __syncthreads();
    #pragma unroll
    for (int pass = 0; pass < 2; ++pass){
      int chunk = (pass << 8) + tid;
      int row = chunk >> 3, c8 = (chunk & 7) << 3;
      *(uint4*)&x_lds[row][c8] = *(const uint4*)(xb + (size_t)(t0 + row)*256 + k0 + c8);
    }
    __syncthreads();
    short8 wa0 = *(const short8*)(wrow + k0 + (quad << 3));
    short8 wa1 = *(const short8*)(wrow + k0 + 32 + (quad << 3));
    #pragma unroll
    for (int nt = 0; nt < 4; ++nt){
      short8 xb0 = *(const short8*)&x_lds[(nt << 4) + l15][quad << 3];
      short8 xb1 = *(const short8*)&x_lds[(nt << 4) + l15][32 + (quad << 3)];
      acc[nt] = __builtin_amdgcn_mfma_f32_16x16x32_bf16(wa0, xb0, acc[nt], 0, 0, 0);
      acc[nt] = __builtin_amdgcn_mfma_f32_16x16x32_bf16(wa1, xb1, acc[nt], 0, 0, 0);
    }
  }
  #pragma unroll
  for (int r = 0; r < 4; ++r){
    int o = o0 + (w << 4) + (quad << 2) + r;
    float bsv = bias[o];
    #pragma unroll
    for (int nt = 0; nt < 4; ++nt){
      size_t idx = ((size_t)(b*CCH + o))*TT + t0 + (nt << 4) + l15;
      out[idx] = acc[nt][r] + bsv + x[idx];
    }
  }
}

extern "C" void kernel_launch(void* const* d_in, const int* in_sizes, int n_in,
                              void* d_out, int out_size, void* d_ws, size_t ws_size,
                              hipStream_t stream){
  const float* x      = (const float*)d_in[0];
  const float* gn_w   = (const float*)d_in[1];
  const float* gn_b   = (const float*)d_in[2];
  const float* qkv_w  = (const float*)d_in[3];
  const float* qkv_b  = (const float*)d_in[4];
  const float* proj_w = (const float*)d_in[5];
  const float* proj_b = (const float*)d_in[6];
  float* out = (float*)d_out;

  float* stats = (float*)d_ws;
  unsigned short* wq_bf = (unsigned short*)(stats + 1024);
  unsigned short* wp_bf = wq_bf + (size_t)768*256;
  unsigned short* xnT   = wp_bf + (size_t)256*256;
  unsigned short* qT    = xnT + (size_t)4*TT*256;
  unsigned short* kT    = qT  + (size_t)16*TT*64;
  unsigned short* vO    = kT  + (size_t)16*TT*64;
  unsigned short* aT    = vO  + (size_t)16*64*TT;

  wconv_gn<<<384, 256, 0, stream>>>(qkv_w, proj_w, x, wq_bf, wp_bf, stats);
  gn_apply_t<<<dim3(64, 4, 4), 256, 0, stream>>>(x, gn_w, gn_b, stats, xnT);
  qkv_mfma<<<dim3(64, 12, 4), 256, 0, stream>>>(wq_bf, qkv_b, xnT, qT, kT, vO);
  attn5<<<1024, 256, 0, stream>>>(qT, kT, vO, aT);
  proj_mfma<<<dim3(64, 4, 4), 256, 0, stream>>>(wp_bf, proj_b, aT, x, out);
}